// Round 21
// baseline (60.605 us; speedup 1.0000x reference)
//
#include <hip/hip_runtime.h>
#include <hip/hip_bf16.h>

#define S_LEN 512
#define EMB   512
#define NHEAD 8
#define DPH   64
#define NREL  3
#define BATCH 8

typedef __attribute__((ext_vector_type(8))) short bf16x8;
typedef __attribute__((ext_vector_type(4))) float f32x4;

__device__ __forceinline__ float bf2f(unsigned short u) {
    union { unsigned int i; float f; } cv;
    cv.i = ((unsigned int)u) << 16;
    return cv.f;
}
__device__ __forceinline__ unsigned short f2bf(float f) {
    __hip_bfloat16 h = __float2bfloat16(f);
    return *reinterpret_cast<unsigned short*>(&h);
}

// global -> LDS direct DMA, 16 B per lane. lds base wave-uniform; lane l
// writes lds + l*16. Source address per-lane.
__device__ __forceinline__ void gload_lds16(const unsigned short* g, unsigned char* lds) {
    __builtin_amdgcn_global_load_lds(
        (const __attribute__((address_space(1))) void*)g,
        (__attribute__((address_space(3))) void*)lds, 16, 0, 0);
}

// ---------------------------------------------------------------------------
// Weight transpose: Wt[z][n][k] (bf16) = W[z][k][n] (f32), z in {q,k,v,o}.
// ---------------------------------------------------------------------------
__global__ __launch_bounds__(256) void transpose_w(
    const float* __restrict__ Wq, const float* __restrict__ Wk,
    const float* __restrict__ Wv, const float* __restrict__ Wo,
    unsigned short* __restrict__ Wt)
{
    const int z = blockIdx.z;
    const float* W = (z == 0) ? Wq : (z == 1) ? Wk : (z == 2) ? Wv : Wo;
    unsigned short* dst = Wt + (size_t)z * EMB * EMB;

    __shared__ float tile[64][65];
    const int n0 = blockIdx.x * 64, k0 = blockIdx.y * 64;
    const int t = threadIdx.x;
    const int cr = t >> 4, cc = (t & 15) * 4;

    #pragma unroll
    for (int it = 0; it < 4; ++it) {
        int r = cr + it * 16;
        float4 v = *reinterpret_cast<const float4*>(W + (size_t)(k0 + r) * EMB + n0 + cc);
        tile[r][cc + 0] = v.x; tile[r][cc + 1] = v.y;
        tile[r][cc + 2] = v.z; tile[r][cc + 3] = v.w;
    }
    __syncthreads();
    #pragma unroll
    for (int it = 0; it < 4; ++it) {
        int n = cr + it * 16;
        ushort4 o;
        o.x = f2bf(tile[cc + 0][n]); o.y = f2bf(tile[cc + 1][n]);
        o.z = f2bf(tile[cc + 2][n]); o.w = f2bf(tile[cc + 3][n]);
        *reinterpret_cast<ushort4*>(dst + (size_t)(n0 + n) * EMB + k0 + cc) = o;
    }
}

// ---------------------------------------------------------------------------
// MFMA projection GEMM, 64x128 tile (M x N), BK=64, 4 waves 2x2
// (wave = 32x64). grid (4, 64, 3) = 768 blocks = 3/CU balanced.
// ---------------------------------------------------------------------------
__global__ __launch_bounds__(256) void gemm_proj_mfma(
    const float* __restrict__ Aq, const float* __restrict__ Ak, const float* __restrict__ Av,
    const unsigned short* __restrict__ Wt,
    const float* __restrict__ bqp, const float* __restrict__ bkp, const float* __restrict__ bvp,
    unsigned short* __restrict__ oq, unsigned short* __restrict__ okp, unsigned short* __restrict__ ov)
{
    const int z = blockIdx.z;
    const float* A = (z == 0) ? Aq : (z == 1) ? Ak : Av;
    const unsigned short* W = Wt + (size_t)z * EMB * EMB;
    const float* bias = (z == 0) ? bqp : (z == 1) ? bkp : bvp;
    unsigned short* out = (z == 0) ? oq : (z == 1) ? okp : ov;

    const int n0 = blockIdx.x * 128;
    const int m0 = blockIdx.y * 64;
    const int tid = threadIdx.x;
    const int lane = tid & 63;
    const int wid = tid >> 6;
    const int wr = wid >> 1, wc = wid & 1;

    __shared__ __align__(16) unsigned char smA[64 * 64 * 2];
    __shared__ __align__(16) unsigned char smB[128 * 64 * 2];

    f32x4 acc[2][4] = {};

    for (int k0 = 0; k0 < EMB; k0 += 64) {
        __syncthreads();
        #pragma unroll
        for (int it = 0; it < 4; ++it) {
            int row = (it * 4 + wid) * 8 + (lane >> 3);
            int kcg = (lane & 7) ^ (row & 7);
            gload_lds16(W + (size_t)(n0 + row) * EMB + k0 + kcg * 8,
                        smB + (it * 4 + wid) * 1024);
        }
        #pragma unroll
        for (int it = 0; it < 2; ++it) {
            int w = it * 256 + tid;
            int row = w >> 3, kc = w & 7;
            const float* src = A + (size_t)(m0 + row) * EMB + k0 + kc * 8;
            float4 v0 = *reinterpret_cast<const float4*>(src);
            float4 v1 = *reinterpret_cast<const float4*>(src + 4);
            union { unsigned short s[8]; uint4 u; } p;
            p.s[0] = f2bf(v0.x); p.s[1] = f2bf(v0.y); p.s[2] = f2bf(v0.z); p.s[3] = f2bf(v0.w);
            p.s[4] = f2bf(v1.x); p.s[5] = f2bf(v1.y); p.s[6] = f2bf(v1.z); p.s[7] = f2bf(v1.w);
            unsigned byte = ((unsigned)row << 7) + ((unsigned)kc << 4);
            byte ^= (unsigned)((row & 7) << 4);
            *reinterpret_cast<uint4*>(smA + byte) = p.u;
        }
        __syncthreads();

        #pragma unroll
        for (int ks = 0; ks < 2; ++ks) {
            bf16x8 bfrag[4];
            #pragma unroll
            for (int ni = 0; ni < 4; ++ni) {
                int col = wc * 64 + ni * 16 + (lane & 15);
                unsigned byte = ((unsigned)col << 7) + (unsigned)(ks << 6) + (unsigned)((lane >> 4) << 4);
                byte ^= (unsigned)((col & 7) << 4);
                bfrag[ni] = *reinterpret_cast<const bf16x8*>(smB + byte);
            }
            #pragma unroll
            for (int mi = 0; mi < 2; ++mi) {
                int row = wr * 32 + mi * 16 + (lane & 15);
                unsigned byte = ((unsigned)row << 7) + (unsigned)(ks << 6) + (unsigned)((lane >> 4) << 4);
                byte ^= (unsigned)((row & 7) << 4);
                bf16x8 afrag = *reinterpret_cast<const bf16x8*>(smA + byte);
                #pragma unroll
                for (int ni = 0; ni < 4; ++ni)
                    acc[mi][ni] = __builtin_amdgcn_mfma_f32_16x16x32_bf16(afrag, bfrag[ni], acc[mi][ni], 0, 0, 0);
            }
        }
    }

    if (z == 2) {
        #pragma unroll
        for (int ni = 0; ni < 4; ++ni) {
            int colg = n0 + wc * 64 + ni * 16 + (lane & 15);
            float bj = bias[colg];
            int hh = colg >> 6, dd = colg & 63;
            #pragma unroll
            for (int mi = 0; mi < 2; ++mi) {
                int rbase = m0 + wr * 32 + mi * 16 + ((lane >> 4) << 2);
                int bb = rbase >> 9, ss = rbase & 511;
                ushort4 o;
                o.x = f2bf(acc[mi][ni][0] + bj);
                o.y = f2bf(acc[mi][ni][1] + bj);
                o.z = f2bf(acc[mi][ni][2] + bj);
                o.w = f2bf(acc[mi][ni][3] + bj);
                *reinterpret_cast<ushort4*>(out + ((size_t)(bb * NHEAD + hh) * DPH + dd) * S_LEN + ss) = o;
            }
        }
    } else {
        #pragma unroll
        for (int ni = 0; ni < 4; ++ni) {
            int colg = n0 + wc * 64 + ni * 16 + (lane & 15);
            float bj = bias[colg];
            #pragma unroll
            for (int mi = 0; mi < 2; ++mi) {
                int rbase = m0 + wr * 32 + mi * 16 + ((lane >> 4) << 2);
                #pragma unroll
                for (int q = 0; q < 4; ++q)
                    out[(size_t)(rbase + q) * EMB + colg] = f2bf(acc[mi][ni][q] + bj);
            }
        }
    }
}

// ---------------------------------------------------------------------------
// MFMA output GEMM, 64x128 tile, grid (4, 64) = 256 blocks = 1/CU.
// ---------------------------------------------------------------------------
__global__ __launch_bounds__(256) void gemm_out_mfma(
    const unsigned short* __restrict__ A,
    const unsigned short* __restrict__ W,
    const float* __restrict__ bias,
    float* __restrict__ out)
{
    const int n0 = blockIdx.x * 128;
    const int m0 = blockIdx.y * 64;
    const int tid = threadIdx.x;
    const int lane = tid & 63;
    const int wid = tid >> 6;
    const int wr = wid >> 1, wc = wid & 1;

    __shared__ __align__(16) unsigned char smA[64 * 64 * 2];
    __shared__ __align__(16) unsigned char smB[128 * 64 * 2];

    f32x4 acc[2][4] = {};

    for (int k0 = 0; k0 < EMB; k0 += 64) {
        __syncthreads();
        #pragma unroll
        for (int it = 0; it < 4; ++it) {
            int row = (it * 4 + wid) * 8 + (lane >> 3);
            int kcg = (lane & 7) ^ (row & 7);
            gload_lds16(W + (size_t)(n0 + row) * EMB + k0 + kcg * 8,
                        smB + (it * 4 + wid) * 1024);
        }
        #pragma unroll
        for (int it = 0; it < 2; ++it) {
            int row = (it * 4 + wid) * 8 + (lane >> 3);
            int kcg = (lane & 7) ^ (row & 7);
            gload_lds16(A + (size_t)(m0 + row) * EMB + k0 + kcg * 8,
                        smA + (it * 4 + wid) * 1024);
        }
        __syncthreads();

        #pragma unroll
        for (int ks = 0; ks < 2; ++ks) {
            bf16x8 bfrag[4];
            #pragma unroll
            for (int ni = 0; ni < 4; ++ni) {
                int col = wc * 64 + ni * 16 + (lane & 15);
                unsigned byte = ((unsigned)col << 7) + (unsigned)(ks << 6) + (unsigned)((lane >> 4) << 4);
                byte ^= (unsigned)((col & 7) << 4);
                bfrag[ni] = *reinterpret_cast<const bf16x8*>(smB + byte);
            }
            #pragma unroll
            for (int mi = 0; mi < 2; ++mi) {
                int row = wr * 32 + mi * 16 + (lane & 15);
                unsigned byte = ((unsigned)row << 7) + (unsigned)(ks << 6) + (unsigned)((lane >> 4) << 4);
                byte ^= (unsigned)((row & 7) << 4);
                bf16x8 afrag = *reinterpret_cast<const bf16x8*>(smA + byte);
                #pragma unroll
                for (int ni = 0; ni < 4; ++ni)
                    acc[mi][ni] = __builtin_amdgcn_mfma_f32_16x16x32_bf16(afrag, bfrag[ni], acc[mi][ni], 0, 0, 0);
            }
        }
    }

    #pragma unroll
    for (int ni = 0; ni < 4; ++ni) {
        int colg = n0 + wc * 64 + ni * 16 + (lane & 15);
        float bj = bias[colg];
        #pragma unroll
        for (int mi = 0; mi < 2; ++mi) {
            int rbase = m0 + wr * 32 + mi * 16 + ((lane >> 4) << 2);
            #pragma unroll
            for (int q = 0; q < 4; ++q)
                out[(size_t)(rbase + q) * EMB + colg] = acc[mi][ni][q] + bj;
        }
    }
}

// ---------------------------------------------------------------------------
// Relation-aware flash attention, v12: gload_lds double-buffered K/V,
// 32-t tiles (8 per t-group), ONE barrier per tile. DMA for tile i+1 is
// issued before compute(i) and drained by the barrier AFTER compute(i):
// memory latency fully overlapped, no register round-trip.
// Layouts: K [32t][64d] swz ^((row&7)<<4); V^T [64d][32t] swz ^((d&3)<<4);
// P [16][32] swz ^((sl&3)<<4). gload sources pre-swizzled (rule #21).
// ---------------------------------------------------------------------------
__global__ __launch_bounds__(512) void attn_mfma(
    const unsigned short* __restrict__ qb,
    const unsigned short* __restrict__ kb,
    const unsigned short* __restrict__ vbT,
    const int* __restrict__ rel,
    const float* __restrict__ rel_k, const float* __restrict__ rel_v,
    unsigned short* __restrict__ ob)
{
    const int gid = blockIdx.x + 8 * (blockIdx.y + 8 * blockIdx.z);
    const int bh  = (gid & 7) + 8 * ((gid >> 3) & 7);
    const int s0  = (gid >> 6) * 64;
    const int h   = bh & 7;
    const int b   = bh >> 3;
    const int tid = threadIdx.x;
    const int lane = tid & 63;
    const int wid = tid >> 6;          // 0..7
    const int qstrip = wid & 3;        // 16-row strip
    const int tgroup = wid >> 2;       // t-half
    const int wg = wid & 3;            // wave index within t-group
    const int sl = lane & 15;
    const int tg = lane >> 4;

    __shared__ __align__(16) unsigned char smQ[8192];        // Q; P waves 0-3
    __shared__ __align__(16) unsigned char smK[16384];       // [tgroup][buf][4KB]; accL after loop
    __shared__ __align__(16) unsigned char smVt[16384];      // [tgroup][buf][4KB]; stats after loop
    __shared__ __align__(16) unsigned char smP2[4096];       // P waves 4-7
    __shared__ float qrel_s[64][4];
    __shared__ float relv_s[NREL][64];

    const unsigned short* qsrc  = qb + ((size_t)(b * S_LEN + s0)) * EMB + h * DPH;
    const unsigned short* ksrc  = kb + ((size_t)b * S_LEN) * EMB + h * DPH;
    const unsigned short* vsrcT = vbT + (size_t)(b * NHEAD + h) * DPH * S_LEN;

    // --- stage Q (64x64 bf16, swizzled): 512 thr x 1 uint4 ---
    {
        int row = tid >> 3, kc = tid & 7;
        uint4 raw = *reinterpret_cast<const uint4*>(qsrc + (size_t)row * EMB + kc * 8);
        unsigned byte = ((unsigned)row << 7) + ((unsigned)kc << 4);
        byte ^= (unsigned)((row & 7) << 4);
        *reinterpret_cast<uint4*>(smQ + byte) = raw;
    }
    if (tid < NREL * 64) {
        int rr = tid >> 6, d = tid & 63;
        relv_s[rr][d] = rel_v[rr * DPH + d];
    }
    __syncthreads();
    if (tid < 192) {
        int r = tid / 3, rr = tid - 3 * (tid / 3);
        float s = 0.f;
        #pragma unroll
        for (int dc = 0; dc < 32; ++dc) {
            unsigned byte = ((unsigned)r << 7) + (unsigned)(dc << 2);
            byte ^= (unsigned)((r & 7) << 4);
            unsigned u = *reinterpret_cast<const unsigned*>(smQ + byte);
            s += bf2f((unsigned short)(u & 0xffff)) * rel_k[rr * DPH + dc * 2]
               + bf2f((unsigned short)(u >> 16))   * rel_k[rr * DPH + dc * 2 + 1];
        }
        qrel_s[r][rr] = s;
    }
    __syncthreads();

    const int srow = qstrip * 16 + sl;
    const float CEXP  = 0.125f * 1.4426950408889634f;
    const float SHIFT = 11.541560327111707f;           // 8 * log2(e)
    const float qa0 = qrel_s[srow][0] * CEXP - SHIFT;
    const float qa1 = qrel_s[srow][1] * CEXP - SHIFT;
    const float qa2 = qrel_s[srow][2] * CEXP - SHIFT;

    bf16x8 qfrag[2];
    #pragma unroll
    for (int ks = 0; ks < 2; ++ks) {
        unsigned byte = ((unsigned)srow << 7) + (unsigned)(ks << 6) + (unsigned)(tg << 4);
        byte ^= (unsigned)((srow & 7) << 4);
        qfrag[ks] = *reinterpret_cast<const bf16x8*>(smQ + byte);
    }
    // smQ's Q dead from here; waves 0-3 write P into it after the prologue
    // barrier below (all qfrag reads complete before any wave passes it).

    const int* rrow_s = rel + ((size_t)(b * S_LEN + s0 + srow)) * S_LEN;
    unsigned char* pb = (wid < 4) ? (smQ + wid * 1024) : (smP2 + (wid - 4) * 1024);

    // gload source indices (per thread): gtid = wg*64 + lane-in-wave
    const int krow = wg * 8 + ((lane & 63) >> 3);       // 0..31
    const int kcg  = (lane & 7) ^ (krow & 7);
    const int vd   = wg * 16 + (lane >> 2);             // 0..63
    const int vtcg = (lane & 3) ^ (vd & 3);
    unsigned char* kbuf0 = smK  + tgroup * 8192;        // [buf][4KB]
    unsigned char* vbuf0 = smVt + tgroup * 8192;

    float l_run = 0.f, es1 = 0.f, es2 = 0.f;
    f32x4 acc_pv[4] = {};

    // prologue: DMA tile 0 into buf 0
    {
        const int t0 = tgroup * 256;
        gload_lds16(ksrc + (size_t)(t0 + krow) * EMB + kcg * 8, kbuf0 + wg * 1024);
        gload_lds16(vsrcT + (size_t)vd * S_LEN + t0 + vtcg * 8, vbuf0 + wg * 1024);
    }
    __syncthreads();   // drains tile-0 DMA

    #pragma unroll
    for (int i = 0; i < 8; ++i) {
        const int t0 = tgroup * 256 + i * 32;
        const int cur = i & 1;
        unsigned char* kcur = kbuf0 + cur * 4096;
        unsigned char* vcur = vbuf0 + cur * 4096;

        // issue next tile's DMA into the other buffer (overlaps compute)
        if (i < 7) {
            const int t0n = t0 + 32;
            gload_lds16(ksrc + (size_t)(t0n + krow) * EMB + kcg * 8,
                        kbuf0 + (cur ^ 1) * 4096 + wg * 1024);
            gload_lds16(vsrcT + (size_t)vd * S_LEN + t0n + vtcg * 8,
                        vbuf0 + (cur ^ 1) * 4096 + wg * 1024);
        }

        // rel indices for this tile (latency hides under QK MFMA)
        int4 rr0 = *reinterpret_cast<const int4*>(rrow_s + t0 + tg * 4);
        int4 rr1 = *reinterpret_cast<const int4*>(rrow_s + t0 + 16 + tg * 4);

        // ---- QK^T: C[t][s], 32 t x 16 s ----
        f32x4 sacc[2] = {};
        #pragma unroll
        for (int ks = 0; ks < 2; ++ks)
            #pragma unroll
            for (int t4 = 0; t4 < 2; ++t4) {
                int trow = t4 * 16 + sl;
                unsigned byte = ((unsigned)trow << 7) + (unsigned)(ks << 6) + (unsigned)(tg << 4);
                byte ^= (unsigned)((trow & 7) << 4);
                bf16x8 kf = *reinterpret_cast<const bf16x8*>(kcur + byte);
                sacc[t4] = __builtin_amdgcn_mfma_f32_16x16x32_bf16(kf, qfrag[ks], sacc[t4], 0, 0, 0);
            }

        // ---- no-max softmax + masked es ----
        #pragma unroll
        for (int t4 = 0; t4 < 2; ++t4) {
            int4 rrx = (t4 == 0) ? rr0 : rr1;
            int rv[4] = {rrx.x, rrx.y, rrx.z, rrx.w};
            #pragma unroll
            for (int j = 0; j < 4; ++j) {
                int r = rv[j];
                float qa = (r == 0) ? qa0 : ((r == 1) ? qa1 : qa2);
                float p = __builtin_amdgcn_exp2f(fmaf(sacc[t4][j], CEXP, qa));
                sacc[t4][j] = p;
                l_run += p;
                es1 += (r == 1) ? p : 0.f;
                es2 += (r == 2) ? p : 0.f;
            }
        }

        // P -> LDS bf16 ([16 s][32 t], 64B rows; same-wave write->read)
        #pragma unroll
        for (int t4 = 0; t4 < 2; ++t4)
            #pragma unroll
            for (int pr = 0; pr < 2; ++pr) {
                unsigned u = (unsigned)f2bf(sacc[t4][2 * pr]) |
                             ((unsigned)f2bf(sacc[t4][2 * pr + 1]) << 16);
                unsigned byte = ((unsigned)sl << 6) + (unsigned)(t4 * 32 + tg * 8 + pr * 4);
                byte ^= (unsigned)((sl & 3) << 4);
                *reinterpret_cast<unsigned*>(pb + byte) = u;
            }

        // PV: acc[s][d] += P[s][t] V[t][d]  (K = 32, single mfma per dt)
        unsigned pbyte = ((unsigned)sl << 6) + (unsigned)(tg << 4);
        pbyte ^= (unsigned)((sl & 3) << 4);
        bf16x8 pf = *reinterpret_cast<const bf16x8*>(pb + pbyte);
        #pragma unroll
        for (int dt = 0; dt < 4; ++dt) {
            int d = dt * 16 + sl;
            unsigned vbyte = ((unsigned)d << 6) + (unsigned)(tg << 4);
            vbyte ^= (unsigned)((d & 3) << 4);
            bf16x8 vf = *reinterpret_cast<const bf16x8*>(vcur + vbyte);
            acc_pv[dt] = __builtin_amdgcn_mfma_f32_16x16x32_bf16(pf, vf, acc_pv[dt], 0, 0, 0);
        }

        __syncthreads();   // single barrier: drains DMA(i+1), orders buf reuse
    }

    // end-only cross-lane reduce (row sums over this t-group's 256 t)
    l_run += __shfl_xor(l_run, 16);  l_run += __shfl_xor(l_run, 32);
    es1   += __shfl_xor(es1, 16);    es1   += __shfl_xor(es1, 32);
    es2   += __shfl_xor(es2, 16);    es2   += __shfl_xor(es2, 32);

    // ---- publish partials & merge the two t-groups (weights all 1) ----
    // (loop's final barrier already separates last compute from this reuse)
    float* accL  = reinterpret_cast<float*>(smK);    // [64 rows][64 d] = 16 KB
    float* stats = reinterpret_cast<float*>(smVt);   // l[2][64], es1[2][64], es2[2][64]

    if (tg == 0) {
        stats[tgroup * 64 + srow]        = l_run;
        stats[128 + tgroup * 64 + srow]  = es1;
        stats[256 + tgroup * 64 + srow]  = es2;
    }
    if (tgroup == 1) {
        #pragma unroll
        for (int dt = 0; dt < 4; ++dt)
            #pragma unroll
            for (int r = 0; r < 4; ++r)
                accL[(qstrip * 16 + tg * 4 + r) * 64 + dt * 16 + sl] = acc_pv[dt][r];
    }
    __syncthreads();

    if (tgroup == 0) {
        unsigned short* dst = ob + ((size_t)(b * S_LEN + s0 + qstrip * 16)) * EMB + h * DPH;
        #pragma unroll
        for (int r = 0; r < 4; ++r) {
            const int row64 = qstrip * 16 + tg * 4 + r;
            float lt  = stats[row64]       + stats[64 + row64];
            float e1t = stats[128 + row64] + stats[192 + row64];
            float e2t = stats[256 + row64] + stats[320 + row64];
            float e0t = lt - e1t - e2t;
            float linv = 1.f / lt;
            #pragma unroll
            for (int dt = 0; dt < 4; ++dt) {
                int d = dt * 16 + sl;
                float o = acc_pv[dt][r] + accL[row64 * 64 + d];
                o += e0t * relv_s[0][d] + e1t * relv_s[1][d] + e2t * relv_s[2][d];
                o *= linv;
                dst[(size_t)(tg * 4 + r) * EMB + d] = f2bf(o);
            }
        }
    }
}

extern "C" void kernel_launch(void* const* d_in, const int* in_sizes, int n_in,
                              void* d_out, int out_size, void* d_ws, size_t ws_size,
                              hipStream_t stream) {
    int iq=0, ik=1, iv=2, irel=3, iWq=4, ibq=5, iWk=6, ibk=7, iWv=8, ibv=9, iWo=10, ibo=11, irk=12, irv=13;
    if (n_in >= 14 && in_sizes[0] == 512 * 512) {
        iWk=0; iWo=1; iWq=2; iWv=3; ibk=4; ibo=5; ibq=6; ibv=7;
        irel=8; ik=9; iq=10; irk=11; irv=12; iv=13;
    }

    const float* q_in = (const float*)d_in[iq];
    const float* k_in = (const float*)d_in[ik];
    const float* v_in = (const float*)d_in[iv];
    const int*   grel = (const int*)d_in[irel];
    const float* Wq = (const float*)d_in[iWq];
    const float* bq = (const float*)d_in[ibq];
    const float* Wk = (const float*)d_in[iWk];
    const float* bk = (const float*)d_in[ibk];
    const float* Wv = (const float*)d_in[iWv];
    const float* bv = (const float*)d_in[ibv];
    const float* Wo = (const float*)d_in[iWo];
    const float* bo = (const float*)d_in[ibo];
    const float* rk = (const float*)d_in[irk];
    const float* rv = (const float*)d_in[irv];

    unsigned short* qb  = (unsigned short*)d_ws;
    unsigned short* kb  = qb + (size_t)4096 * 512;
    unsigned short* vbT = kb + (size_t)4096 * 512;   // [b*NHEAD+h][d][s]
    unsigned short* ab  = vbT + (size_t)4096 * 512;
    unsigned short* wt  = ab + (size_t)4096 * 512;

    dim3 blk(256);
    transpose_w<<<dim3(8, 8, 4), blk, 0, stream>>>(Wq, Wk, Wv, Wo, wt);
    gemm_proj_mfma<<<dim3(4, 64, 3), blk, 0, stream>>>(q_in, k_in, v_in, wt, bq, bk, bv, qb, kb, vbT);
    attn_mfma<<<dim3(8, NHEAD, BATCH), dim3(512), 0, stream>>>(qb, kb, vbT, grel, rk, rv, ab);
    gemm_out_mfma<<<dim3(4, 64), blk, 0, stream>>>(ab, wt + (size_t)3 * 512 * 512, bo, (float*)d_out);
}

// Round 22
// 60.553 us; speedup vs baseline: 1.0009x; 1.0009x over previous
//
#include <hip/hip_runtime.h>
#include <hip/hip_bf16.h>

#define S_LEN 512
#define EMB   512
#define NHEAD 8
#define DPH   64
#define NREL  3
#define BATCH 8

typedef __attribute__((ext_vector_type(8))) short bf16x8;
typedef __attribute__((ext_vector_type(4))) float f32x4;

__device__ __forceinline__ float bf2f(unsigned short u) {
    union { unsigned int i; float f; } cv;
    cv.i = ((unsigned int)u) << 16;
    return cv.f;
}
__device__ __forceinline__ unsigned short f2bf(float f) {
    __hip_bfloat16 h = __float2bfloat16(f);
    return *reinterpret_cast<unsigned short*>(&h);
}

// global -> LDS direct DMA, 16 B per lane. lds base wave-uniform; lane l
// writes lds + l*16. Source address per-lane.
__device__ __forceinline__ void gload_lds16(const unsigned short* g, unsigned char* lds) {
    __builtin_amdgcn_global_load_lds(
        (const __attribute__((address_space(1))) void*)g,
        (__attribute__((address_space(3))) void*)lds, 16, 0, 0);
}

// ---------------------------------------------------------------------------
// Weight transpose: Wt[z][n][k] (bf16) = W[z][k][n] (f32), z in {q,k,v,o}.
// ---------------------------------------------------------------------------
__global__ __launch_bounds__(256) void transpose_w(
    const float* __restrict__ Wq, const float* __restrict__ Wk,
    const float* __restrict__ Wv, const float* __restrict__ Wo,
    unsigned short* __restrict__ Wt)
{
    const int z = blockIdx.z;
    const float* W = (z == 0) ? Wq : (z == 1) ? Wk : (z == 2) ? Wv : Wo;
    unsigned short* dst = Wt + (size_t)z * EMB * EMB;

    __shared__ float tile[64][65];
    const int n0 = blockIdx.x * 64, k0 = blockIdx.y * 64;
    const int t = threadIdx.x;
    const int cr = t >> 4, cc = (t & 15) * 4;

    #pragma unroll
    for (int it = 0; it < 4; ++it) {
        int r = cr + it * 16;
        float4 v = *reinterpret_cast<const float4*>(W + (size_t)(k0 + r) * EMB + n0 + cc);
        tile[r][cc + 0] = v.x; tile[r][cc + 1] = v.y;
        tile[r][cc + 2] = v.z; tile[r][cc + 3] = v.w;
    }
    __syncthreads();
    #pragma unroll
    for (int it = 0; it < 4; ++it) {
        int n = cr + it * 16;
        ushort4 o;
        o.x = f2bf(tile[cc + 0][n]); o.y = f2bf(tile[cc + 1][n]);
        o.z = f2bf(tile[cc + 2][n]); o.w = f2bf(tile[cc + 3][n]);
        *reinterpret_cast<ushort4*>(dst + (size_t)(n0 + n) * EMB + k0 + cc) = o;
    }
}

// ---------------------------------------------------------------------------
// MFMA projection GEMM, 64x128 tile (M x N), BK=64, 4 waves 2x2
// (wave = 32x64). grid (4, 64, 3) = 768 blocks = 3/CU balanced.
// ---------------------------------------------------------------------------
__global__ __launch_bounds__(256) void gemm_proj_mfma(
    const float* __restrict__ Aq, const float* __restrict__ Ak, const float* __restrict__ Av,
    const unsigned short* __restrict__ Wt,
    const float* __restrict__ bqp, const float* __restrict__ bkp, const float* __restrict__ bvp,
    unsigned short* __restrict__ oq, unsigned short* __restrict__ okp, unsigned short* __restrict__ ov)
{
    const int z = blockIdx.z;
    const float* A = (z == 0) ? Aq : (z == 1) ? Ak : Av;
    const unsigned short* W = Wt + (size_t)z * EMB * EMB;
    const float* bias = (z == 0) ? bqp : (z == 1) ? bkp : bvp;
    unsigned short* out = (z == 0) ? oq : (z == 1) ? okp : ov;

    const int n0 = blockIdx.x * 128;
    const int m0 = blockIdx.y * 64;
    const int tid = threadIdx.x;
    const int lane = tid & 63;
    const int wid = tid >> 6;
    const int wr = wid >> 1, wc = wid & 1;

    __shared__ __align__(16) unsigned char smA[64 * 64 * 2];
    __shared__ __align__(16) unsigned char smB[128 * 64 * 2];

    f32x4 acc[2][4] = {};

    for (int k0 = 0; k0 < EMB; k0 += 64) {
        __syncthreads();
        #pragma unroll
        for (int it = 0; it < 4; ++it) {
            int row = (it * 4 + wid) * 8 + (lane >> 3);
            int kcg = (lane & 7) ^ (row & 7);
            gload_lds16(W + (size_t)(n0 + row) * EMB + k0 + kcg * 8,
                        smB + (it * 4 + wid) * 1024);
        }
        #pragma unroll
        for (int it = 0; it < 2; ++it) {
            int w = it * 256 + tid;
            int row = w >> 3, kc = w & 7;
            const float* src = A + (size_t)(m0 + row) * EMB + k0 + kc * 8;
            float4 v0 = *reinterpret_cast<const float4*>(src);
            float4 v1 = *reinterpret_cast<const float4*>(src + 4);
            union { unsigned short s[8]; uint4 u; } p;
            p.s[0] = f2bf(v0.x); p.s[1] = f2bf(v0.y); p.s[2] = f2bf(v0.z); p.s[3] = f2bf(v0.w);
            p.s[4] = f2bf(v1.x); p.s[5] = f2bf(v1.y); p.s[6] = f2bf(v1.z); p.s[7] = f2bf(v1.w);
            unsigned byte = ((unsigned)row << 7) + ((unsigned)kc << 4);
            byte ^= (unsigned)((row & 7) << 4);
            *reinterpret_cast<uint4*>(smA + byte) = p.u;
        }
        __syncthreads();

        #pragma unroll
        for (int ks = 0; ks < 2; ++ks) {
            bf16x8 bfrag[4];
            #pragma unroll
            for (int ni = 0; ni < 4; ++ni) {
                int col = wc * 64 + ni * 16 + (lane & 15);
                unsigned byte = ((unsigned)col << 7) + (unsigned)(ks << 6) + (unsigned)((lane >> 4) << 4);
                byte ^= (unsigned)((col & 7) << 4);
                bfrag[ni] = *reinterpret_cast<const bf16x8*>(smB + byte);
            }
            #pragma unroll
            for (int mi = 0; mi < 2; ++mi) {
                int row = wr * 32 + mi * 16 + (lane & 15);
                unsigned byte = ((unsigned)row << 7) + (unsigned)(ks << 6) + (unsigned)((lane >> 4) << 4);
                byte ^= (unsigned)((row & 7) << 4);
                bf16x8 afrag = *reinterpret_cast<const bf16x8*>(smA + byte);
                #pragma unroll
                for (int ni = 0; ni < 4; ++ni)
                    acc[mi][ni] = __builtin_amdgcn_mfma_f32_16x16x32_bf16(afrag, bfrag[ni], acc[mi][ni], 0, 0, 0);
            }
        }
    }

    if (z == 2) {
        #pragma unroll
        for (int ni = 0; ni < 4; ++ni) {
            int colg = n0 + wc * 64 + ni * 16 + (lane & 15);
            float bj = bias[colg];
            int hh = colg >> 6, dd = colg & 63;
            #pragma unroll
            for (int mi = 0; mi < 2; ++mi) {
                int rbase = m0 + wr * 32 + mi * 16 + ((lane >> 4) << 2);
                int bb = rbase >> 9, ss = rbase & 511;
                ushort4 o;
                o.x = f2bf(acc[mi][ni][0] + bj);
                o.y = f2bf(acc[mi][ni][1] + bj);
                o.z = f2bf(acc[mi][ni][2] + bj);
                o.w = f2bf(acc[mi][ni][3] + bj);
                *reinterpret_cast<ushort4*>(out + ((size_t)(bb * NHEAD + hh) * DPH + dd) * S_LEN + ss) = o;
            }
        }
    } else {
        #pragma unroll
        for (int ni = 0; ni < 4; ++ni) {
            int colg = n0 + wc * 64 + ni * 16 + (lane & 15);
            float bj = bias[colg];
            #pragma unroll
            for (int mi = 0; mi < 2; ++mi) {
                int rbase = m0 + wr * 32 + mi * 16 + ((lane >> 4) << 2);
                #pragma unroll
                for (int q = 0; q < 4; ++q)
                    out[(size_t)(rbase + q) * EMB + colg] = f2bf(acc[mi][ni][q] + bj);
            }
        }
    }
}

// ---------------------------------------------------------------------------
// MFMA output GEMM, 64x128 tile, grid (4, 64) = 256 blocks = 1/CU.
// ---------------------------------------------------------------------------
__global__ __launch_bounds__(256) void gemm_out_mfma(
    const unsigned short* __restrict__ A,
    const unsigned short* __restrict__ W,
    const float* __restrict__ bias,
    float* __restrict__ out)
{
    const int n0 = blockIdx.x * 128;
    const int m0 = blockIdx.y * 64;
    const int tid = threadIdx.x;
    const int lane = tid & 63;
    const int wid = tid >> 6;
    const int wr = wid >> 1, wc = wid & 1;

    __shared__ __align__(16) unsigned char smA[64 * 64 * 2];
    __shared__ __align__(16) unsigned char smB[128 * 64 * 2];

    f32x4 acc[2][4] = {};

    for (int k0 = 0; k0 < EMB; k0 += 64) {
        __syncthreads();
        #pragma unroll
        for (int it = 0; it < 4; ++it) {
            int row = (it * 4 + wid) * 8 + (lane >> 3);
            int kcg = (lane & 7) ^ (row & 7);
            gload_lds16(W + (size_t)(n0 + row) * EMB + k0 + kcg * 8,
                        smB + (it * 4 + wid) * 1024);
        }
        #pragma unroll
        for (int it = 0; it < 2; ++it) {
            int row = (it * 4 + wid) * 8 + (lane >> 3);
            int kcg = (lane & 7) ^ (row & 7);
            gload_lds16(A + (size_t)(m0 + row) * EMB + k0 + kcg * 8,
                        smA + (it * 4 + wid) * 1024);
        }
        __syncthreads();

        #pragma unroll
        for (int ks = 0; ks < 2; ++ks) {
            bf16x8 bfrag[4];
            #pragma unroll
            for (int ni = 0; ni < 4; ++ni) {
                int col = wc * 64 + ni * 16 + (lane & 15);
                unsigned byte = ((unsigned)col << 7) + (unsigned)(ks << 6) + (unsigned)((lane >> 4) << 4);
                byte ^= (unsigned)((col & 7) << 4);
                bfrag[ni] = *reinterpret_cast<const bf16x8*>(smB + byte);
            }
            #pragma unroll
            for (int mi = 0; mi < 2; ++mi) {
                int row = wr * 32 + mi * 16 + (lane & 15);
                unsigned byte = ((unsigned)row << 7) + (unsigned)(ks << 6) + (unsigned)((lane >> 4) << 4);
                byte ^= (unsigned)((row & 7) << 4);
                bf16x8 afrag = *reinterpret_cast<const bf16x8*>(smA + byte);
                #pragma unroll
                for (int ni = 0; ni < 4; ++ni)
                    acc[mi][ni] = __builtin_amdgcn_mfma_f32_16x16x32_bf16(afrag, bfrag[ni], acc[mi][ni], 0, 0, 0);
            }
        }
    }

    #pragma unroll
    for (int ni = 0; ni < 4; ++ni) {
        int colg = n0 + wc * 64 + ni * 16 + (lane & 15);
        float bj = bias[colg];
        #pragma unroll
        for (int mi = 0; mi < 2; ++mi) {
            int rbase = m0 + wr * 32 + mi * 16 + ((lane >> 4) << 2);
            #pragma unroll
            for (int q = 0; q < 4; ++q)
                out[(size_t)(rbase + q) * EMB + colg] = acc[mi][ni][q] + bj;
        }
    }
}

// ---------------------------------------------------------------------------
// Relation-aware flash attention, v12: gload_lds double-buffered K/V,
// 32-t tiles (8 per t-group), ONE barrier per tile. DMA for tile i+1 is
// issued before compute(i) and drained by the barrier AFTER compute(i):
// memory latency fully overlapped, no register round-trip.
// Layouts: K [32t][64d] swz ^((row&7)<<4); V^T [64d][32t] swz ^((d&3)<<4);
// P [16][32] swz ^((sl&3)<<4). gload sources pre-swizzled (rule #21).
// ---------------------------------------------------------------------------
__global__ __launch_bounds__(512) void attn_mfma(
    const unsigned short* __restrict__ qb,
    const unsigned short* __restrict__ kb,
    const unsigned short* __restrict__ vbT,
    const int* __restrict__ rel,
    const float* __restrict__ rel_k, const float* __restrict__ rel_v,
    unsigned short* __restrict__ ob)
{
    const int gid = blockIdx.x + 8 * (blockIdx.y + 8 * blockIdx.z);
    const int bh  = (gid & 7) + 8 * ((gid >> 3) & 7);
    const int s0  = (gid >> 6) * 64;
    const int h   = bh & 7;
    const int b   = bh >> 3;
    const int tid = threadIdx.x;
    const int lane = tid & 63;
    const int wid = tid >> 6;          // 0..7
    const int qstrip = wid & 3;        // 16-row strip
    const int tgroup = wid >> 2;       // t-half
    const int wg = wid & 3;            // wave index within t-group
    const int sl = lane & 15;
    const int tg = lane >> 4;

    __shared__ __align__(16) unsigned char smQ[8192];        // Q; P waves 0-3
    __shared__ __align__(16) unsigned char smK[16384];       // [tgroup][buf][4KB]; accL after loop
    __shared__ __align__(16) unsigned char smVt[16384];      // [tgroup][buf][4KB]; stats after loop
    __shared__ __align__(16) unsigned char smP2[4096];       // P waves 4-7
    __shared__ float qrel_s[64][4];
    __shared__ float relv_s[NREL][64];

    const unsigned short* qsrc  = qb + ((size_t)(b * S_LEN + s0)) * EMB + h * DPH;
    const unsigned short* ksrc  = kb + ((size_t)b * S_LEN) * EMB + h * DPH;
    const unsigned short* vsrcT = vbT + (size_t)(b * NHEAD + h) * DPH * S_LEN;

    // --- stage Q (64x64 bf16, swizzled): 512 thr x 1 uint4 ---
    {
        int row = tid >> 3, kc = tid & 7;
        uint4 raw = *reinterpret_cast<const uint4*>(qsrc + (size_t)row * EMB + kc * 8);
        unsigned byte = ((unsigned)row << 7) + ((unsigned)kc << 4);
        byte ^= (unsigned)((row & 7) << 4);
        *reinterpret_cast<uint4*>(smQ + byte) = raw;
    }
    if (tid < NREL * 64) {
        int rr = tid >> 6, d = tid & 63;
        relv_s[rr][d] = rel_v[rr * DPH + d];
    }
    __syncthreads();
    if (tid < 192) {
        int r = tid / 3, rr = tid - 3 * (tid / 3);
        float s = 0.f;
        #pragma unroll
        for (int dc = 0; dc < 32; ++dc) {
            unsigned byte = ((unsigned)r << 7) + (unsigned)(dc << 2);
            byte ^= (unsigned)((r & 7) << 4);
            unsigned u = *reinterpret_cast<const unsigned*>(smQ + byte);
            s += bf2f((unsigned short)(u & 0xffff)) * rel_k[rr * DPH + dc * 2]
               + bf2f((unsigned short)(u >> 16))   * rel_k[rr * DPH + dc * 2 + 1];
        }
        qrel_s[r][rr] = s;
    }
    __syncthreads();

    const int srow = qstrip * 16 + sl;
    const float CEXP  = 0.125f * 1.4426950408889634f;
    const float SHIFT = 11.541560327111707f;           // 8 * log2(e)
    const float qa0 = qrel_s[srow][0] * CEXP - SHIFT;
    const float qa1 = qrel_s[srow][1] * CEXP - SHIFT;
    const float qa2 = qrel_s[srow][2] * CEXP - SHIFT;

    bf16x8 qfrag[2];
    #pragma unroll
    for (int ks = 0; ks < 2; ++ks) {
        unsigned byte = ((unsigned)srow << 7) + (unsigned)(ks << 6) + (unsigned)(tg << 4);
        byte ^= (unsigned)((srow & 7) << 4);
        qfrag[ks] = *reinterpret_cast<const bf16x8*>(smQ + byte);
    }
    // smQ's Q dead from here; waves 0-3 write P into it after the prologue
    // barrier below (all qfrag reads complete before any wave passes it).

    const int* rrow_s = rel + ((size_t)(b * S_LEN + s0 + srow)) * S_LEN;
    unsigned char* pb = (wid < 4) ? (smQ + wid * 1024) : (smP2 + (wid - 4) * 1024);

    // gload source indices (per thread): gtid = wg*64 + lane-in-wave
    const int krow = wg * 8 + ((lane & 63) >> 3);       // 0..31
    const int kcg  = (lane & 7) ^ (krow & 7);
    const int vd   = wg * 16 + (lane >> 2);             // 0..63
    const int vtcg = (lane & 3) ^ (vd & 3);
    unsigned char* kbuf0 = smK  + tgroup * 8192;        // [buf][4KB]
    unsigned char* vbuf0 = smVt + tgroup * 8192;

    float l_run = 0.f, es1 = 0.f, es2 = 0.f;
    f32x4 acc_pv[4] = {};

    // prologue: DMA tile 0 into buf 0
    {
        const int t0 = tgroup * 256;
        gload_lds16(ksrc + (size_t)(t0 + krow) * EMB + kcg * 8, kbuf0 + wg * 1024);
        gload_lds16(vsrcT + (size_t)vd * S_LEN + t0 + vtcg * 8, vbuf0 + wg * 1024);
    }
    __syncthreads();   // drains tile-0 DMA

    #pragma unroll
    for (int i = 0; i < 8; ++i) {
        const int t0 = tgroup * 256 + i * 32;
        const int cur = i & 1;
        unsigned char* kcur = kbuf0 + cur * 4096;
        unsigned char* vcur = vbuf0 + cur * 4096;

        // issue next tile's DMA into the other buffer (overlaps compute)
        if (i < 7) {
            const int t0n = t0 + 32;
            gload_lds16(ksrc + (size_t)(t0n + krow) * EMB + kcg * 8,
                        kbuf0 + (cur ^ 1) * 4096 + wg * 1024);
            gload_lds16(vsrcT + (size_t)vd * S_LEN + t0n + vtcg * 8,
                        vbuf0 + (cur ^ 1) * 4096 + wg * 1024);
        }

        // rel indices for this tile (latency hides under QK MFMA)
        int4 rr0 = *reinterpret_cast<const int4*>(rrow_s + t0 + tg * 4);
        int4 rr1 = *reinterpret_cast<const int4*>(rrow_s + t0 + 16 + tg * 4);

        // ---- QK^T: C[t][s], 32 t x 16 s ----
        f32x4 sacc[2] = {};
        #pragma unroll
        for (int ks = 0; ks < 2; ++ks)
            #pragma unroll
            for (int t4 = 0; t4 < 2; ++t4) {
                int trow = t4 * 16 + sl;
                unsigned byte = ((unsigned)trow << 7) + (unsigned)(ks << 6) + (unsigned)(tg << 4);
                byte ^= (unsigned)((trow & 7) << 4);
                bf16x8 kf = *reinterpret_cast<const bf16x8*>(kcur + byte);
                sacc[t4] = __builtin_amdgcn_mfma_f32_16x16x32_bf16(kf, qfrag[ks], sacc[t4], 0, 0, 0);
            }

        // ---- no-max softmax + masked es ----
        #pragma unroll
        for (int t4 = 0; t4 < 2; ++t4) {
            int4 rrx = (t4 == 0) ? rr0 : rr1;
            int rv[4] = {rrx.x, rrx.y, rrx.z, rrx.w};
            #pragma unroll
            for (int j = 0; j < 4; ++j) {
                int r = rv[j];
                float qa = (r == 0) ? qa0 : ((r == 1) ? qa1 : qa2);
                float p = __builtin_amdgcn_exp2f(fmaf(sacc[t4][j], CEXP, qa));
                sacc[t4][j] = p;
                l_run += p;
                es1 += (r == 1) ? p : 0.f;
                es2 += (r == 2) ? p : 0.f;
            }
        }

        // P -> LDS bf16 ([16 s][32 t], 64B rows; same-wave write->read)
        #pragma unroll
        for (int t4 = 0; t4 < 2; ++t4)
            #pragma unroll
            for (int pr = 0; pr < 2; ++pr) {
                unsigned u = (unsigned)f2bf(sacc[t4][2 * pr]) |
                             ((unsigned)f2bf(sacc[t4][2 * pr + 1]) << 16);
                unsigned byte = ((unsigned)sl << 6) + (unsigned)(t4 * 32 + tg * 8 + pr * 4);
                byte ^= (unsigned)((sl & 3) << 4);
                *reinterpret_cast<unsigned*>(pb + byte) = u;
            }

        // PV: acc[s][d] += P[s][t] V[t][d]  (K = 32, single mfma per dt)
        unsigned pbyte = ((unsigned)sl << 6) + (unsigned)(tg << 4);
        pbyte ^= (unsigned)((sl & 3) << 4);
        bf16x8 pf = *reinterpret_cast<const bf16x8*>(pb + pbyte);
        #pragma unroll
        for (int dt = 0; dt < 4; ++dt) {
            int d = dt * 16 + sl;
            unsigned vbyte = ((unsigned)d << 6) + (unsigned)(tg << 4);
            vbyte ^= (unsigned)((d & 3) << 4);
            bf16x8 vf = *reinterpret_cast<const bf16x8*>(vcur + vbyte);
            acc_pv[dt] = __builtin_amdgcn_mfma_f32_16x16x32_bf16(pf, vf, acc_pv[dt], 0, 0, 0);
        }

        __syncthreads();   // single barrier: drains DMA(i+1), orders buf reuse
    }

    // end-only cross-lane reduce (row sums over this t-group's 256 t)
    l_run += __shfl_xor(l_run, 16);  l_run += __shfl_xor(l_run, 32);
    es1   += __shfl_xor(es1, 16);    es1   += __shfl_xor(es1, 32);
    es2   += __shfl_xor(es2, 16);    es2   += __shfl_xor(es2, 32);

    // ---- publish partials & merge the two t-groups (weights all 1) ----
    // (loop's final barrier already separates last compute from this reuse)
    float* accL  = reinterpret_cast<float*>(smK);    // [64 rows][64 d] = 16 KB
    float* stats = reinterpret_cast<float*>(smVt);   // l[2][64], es1[2][64], es2[2][64]

    if (tg == 0) {
        stats[tgroup * 64 + srow]        = l_run;
        stats[128 + tgroup * 64 + srow]  = es1;
        stats[256 + tgroup * 64 + srow]  = es2;
    }
    if (tgroup == 1) {
        #pragma unroll
        for (int dt = 0; dt < 4; ++dt)
            #pragma unroll
            for (int r = 0; r < 4; ++r)
                accL[(qstrip * 16 + tg * 4 + r) * 64 + dt * 16 + sl] = acc_pv[dt][r];
    }
    __syncthreads();

    if (tgroup == 0) {
        unsigned short* dst = ob + ((size_t)(b * S_LEN + s0 + qstrip * 16)) * EMB + h * DPH;
        #pragma unroll
        for (int r = 0; r < 4; ++r) {
            const int row64 = qstrip * 16 + tg * 4 + r;
            float lt  = stats[row64]       + stats[64 + row64];
            float e1t = stats[128 + row64] + stats[192 + row64];
            float e2t = stats[256 + row64] + stats[320 + row64];
            float e0t = lt - e1t - e2t;
            float linv = 1.f / lt;
            #pragma unroll
            for (int dt = 0; dt < 4; ++dt) {
                int d = dt * 16 + sl;
                float o = acc_pv[dt][r] + accL[row64 * 64 + d];
                o += e0t * relv_s[0][d] + e1t * relv_s[1][d] + e2t * relv_s[2][d];
                o *= linv;
                dst[(size_t)(tg * 4 + r) * EMB + d] = f2bf(o);
            }
        }
    }
}

extern "C" void kernel_launch(void* const* d_in, const int* in_sizes, int n_in,
                              void* d_out, int out_size, void* d_ws, size_t ws_size,
                              hipStream_t stream) {
    int iq=0, ik=1, iv=2, irel=3, iWq=4, ibq=5, iWk=6, ibk=7, iWv=8, ibv=9, iWo=10, ibo=11, irk=12, irv=13;
    if (n_in >= 14 && in_sizes[0] == 512 * 512) {
        iWk=0; iWo=1; iWq=2; iWv=3; ibk=4; ibo=5; ibq=6; ibv=7;
        irel=8; ik=9; iq=10; irk=11; irv=12; iv=13;
    }

    const float* q_in = (const float*)d_in[iq];
    const float* k_in = (const float*)d_in[ik];
    const float* v_in = (const float*)d_in[iv];
    const int*   grel = (const int*)d_in[irel];
    const float* Wq = (const float*)d_in[iWq];
    const float* bq = (const float*)d_in[ibq];
    const float* Wk = (const float*)d_in[iWk];
    const float* bk = (const float*)d_in[ibk];
    const float* Wv = (const float*)d_in[iWv];
    const float* bv = (const float*)d_in[ibv];
    const float* Wo = (const float*)d_in[iWo];
    const float* bo = (const float*)d_in[ibo];
    const float* rk = (const float*)d_in[irk];
    const float* rv = (const float*)d_in[irv];

    unsigned short* qb  = (unsigned short*)d_ws;
    unsigned short* kb  = qb + (size_t)4096 * 512;
    unsigned short* vbT = kb + (size_t)4096 * 512;   // [b*NHEAD+h][d][s]
    unsigned short* ab  = vbT + (size_t)4096 * 512;
    unsigned short* wt  = ab + (size_t)4096 * 512;

    dim3 blk(256);
    transpose_w<<<dim3(8, 8, 4), blk, 0, stream>>>(Wq, Wk, Wv, Wo, wt);
    gemm_proj_mfma<<<dim3(4, 64, 3), blk, 0, stream>>>(q_in, k_in, v_in, wt, bq, bk, bv, qb, kb, vbT);
    attn_mfma<<<dim3(8, NHEAD, BATCH), dim3(512), 0, stream>>>(qb, kb, vbT, grel, rk, rv, ab);
    gemm_out_mfma<<<dim3(4, 64), blk, 0, stream>>>(ab, wt + (size_t)3 * 512 * 512, bo, (float*)d_out);
}

// Round 23
// 56.691 us; speedup vs baseline: 1.0690x; 1.0681x over previous
//
#include <hip/hip_runtime.h>
#include <hip/hip_bf16.h>

#define S_LEN 512
#define EMB   512
#define NHEAD 8
#define DPH   64
#define NREL  3
#define BATCH 8

typedef __attribute__((ext_vector_type(8))) short bf16x8;
typedef __attribute__((ext_vector_type(4))) float f32x4;

__device__ __forceinline__ float bf2f(unsigned short u) {
    union { unsigned int i; float f; } cv;
    cv.i = ((unsigned int)u) << 16;
    return cv.f;
}
__device__ __forceinline__ unsigned short f2bf(float f) {
    __hip_bfloat16 h = __float2bfloat16(f);
    return *reinterpret_cast<unsigned short*>(&h);
}

// global -> LDS direct DMA, 16 B per lane. lds base wave-uniform; lane l
// writes lds + l*16. Source address per-lane.
__device__ __forceinline__ void gload_lds16(const unsigned short* g, unsigned char* lds) {
    __builtin_amdgcn_global_load_lds(
        (const __attribute__((address_space(1))) void*)g,
        (__attribute__((address_space(3))) void*)lds, 16, 0, 0);
}

// ---------------------------------------------------------------------------
// Weight transpose: Wt[z][n][k] (bf16) = W[z][k][n] (f32), z in {q,k,v,o}.
// ---------------------------------------------------------------------------
__global__ __launch_bounds__(256) void transpose_w(
    const float* __restrict__ Wq, const float* __restrict__ Wk,
    const float* __restrict__ Wv, const float* __restrict__ Wo,
    unsigned short* __restrict__ Wt)
{
    const int z = blockIdx.z;
    const float* W = (z == 0) ? Wq : (z == 1) ? Wk : (z == 2) ? Wv : Wo;
    unsigned short* dst = Wt + (size_t)z * EMB * EMB;

    __shared__ float tile[64][65];
    const int n0 = blockIdx.x * 64, k0 = blockIdx.y * 64;
    const int t = threadIdx.x;
    const int cr = t >> 4, cc = (t & 15) * 4;

    #pragma unroll
    for (int it = 0; it < 4; ++it) {
        int r = cr + it * 16;
        float4 v = *reinterpret_cast<const float4*>(W + (size_t)(k0 + r) * EMB + n0 + cc);
        tile[r][cc + 0] = v.x; tile[r][cc + 1] = v.y;
        tile[r][cc + 2] = v.z; tile[r][cc + 3] = v.w;
    }
    __syncthreads();
    #pragma unroll
    for (int it = 0; it < 4; ++it) {
        int n = cr + it * 16;
        ushort4 o;
        o.x = f2bf(tile[cc + 0][n]); o.y = f2bf(tile[cc + 1][n]);
        o.z = f2bf(tile[cc + 2][n]); o.w = f2bf(tile[cc + 3][n]);
        *reinterpret_cast<ushort4*>(dst + (size_t)(n0 + n) * EMB + k0 + cc) = o;
    }
}

// ---------------------------------------------------------------------------
// MFMA projection GEMM, 64x128 tile (M x N), BK=64, 4 waves 2x2
// (wave = 32x64). grid (4, 64, 3) = 768 blocks = 3/CU balanced.
// B staged via global_load_lds w=16 (linear dest + pre-swizzled source).
// z==2 (V) writes TRANSPOSED per-head: vbT[(b*NHEAD+h)*DPH + d][s].
// ---------------------------------------------------------------------------
__global__ __launch_bounds__(256) void gemm_proj_mfma(
    const float* __restrict__ Aq, const float* __restrict__ Ak, const float* __restrict__ Av,
    const unsigned short* __restrict__ Wt,
    const float* __restrict__ bqp, const float* __restrict__ bkp, const float* __restrict__ bvp,
    unsigned short* __restrict__ oq, unsigned short* __restrict__ okp, unsigned short* __restrict__ ov)
{
    const int z = blockIdx.z;
    const float* A = (z == 0) ? Aq : (z == 1) ? Ak : Av;
    const unsigned short* W = Wt + (size_t)z * EMB * EMB;
    const float* bias = (z == 0) ? bqp : (z == 1) ? bkp : bvp;
    unsigned short* out = (z == 0) ? oq : (z == 1) ? okp : ov;

    const int n0 = blockIdx.x * 128;
    const int m0 = blockIdx.y * 64;
    const int tid = threadIdx.x;
    const int lane = tid & 63;
    const int wid = tid >> 6;
    const int wr = wid >> 1, wc = wid & 1;

    __shared__ __align__(16) unsigned char smA[64 * 64 * 2];
    __shared__ __align__(16) unsigned char smB[128 * 64 * 2];

    f32x4 acc[2][4] = {};

    for (int k0 = 0; k0 < EMB; k0 += 64) {
        __syncthreads();
        // B: 16 KB via global_load_lds (linear dest, pre-swizzled source)
        #pragma unroll
        for (int it = 0; it < 4; ++it) {
            int row = (it * 4 + wid) * 8 + (lane >> 3);
            int kcg = (lane & 7) ^ (row & 7);
            gload_lds16(W + (size_t)(n0 + row) * EMB + k0 + kcg * 8,
                        smB + (it * 4 + wid) * 1024);
        }
        // A: f32 -> bf16 convert staging (64 rows)
        #pragma unroll
        for (int it = 0; it < 2; ++it) {
            int w = it * 256 + tid;
            int row = w >> 3, kc = w & 7;
            const float* src = A + (size_t)(m0 + row) * EMB + k0 + kc * 8;
            float4 v0 = *reinterpret_cast<const float4*>(src);
            float4 v1 = *reinterpret_cast<const float4*>(src + 4);
            union { unsigned short s[8]; uint4 u; } p;
            p.s[0] = f2bf(v0.x); p.s[1] = f2bf(v0.y); p.s[2] = f2bf(v0.z); p.s[3] = f2bf(v0.w);
            p.s[4] = f2bf(v1.x); p.s[5] = f2bf(v1.y); p.s[6] = f2bf(v1.z); p.s[7] = f2bf(v1.w);
            unsigned byte = ((unsigned)row << 7) + ((unsigned)kc << 4);
            byte ^= (unsigned)((row & 7) << 4);
            *reinterpret_cast<uint4*>(smA + byte) = p.u;
        }
        __syncthreads();

        #pragma unroll
        for (int ks = 0; ks < 2; ++ks) {
            bf16x8 bfrag[4];
            #pragma unroll
            for (int ni = 0; ni < 4; ++ni) {
                int col = wc * 64 + ni * 16 + (lane & 15);
                unsigned byte = ((unsigned)col << 7) + (unsigned)(ks << 6) + (unsigned)((lane >> 4) << 4);
                byte ^= (unsigned)((col & 7) << 4);
                bfrag[ni] = *reinterpret_cast<const bf16x8*>(smB + byte);
            }
            #pragma unroll
            for (int mi = 0; mi < 2; ++mi) {
                int row = wr * 32 + mi * 16 + (lane & 15);
                unsigned byte = ((unsigned)row << 7) + (unsigned)(ks << 6) + (unsigned)((lane >> 4) << 4);
                byte ^= (unsigned)((row & 7) << 4);
                bf16x8 afrag = *reinterpret_cast<const bf16x8*>(smA + byte);
                #pragma unroll
                for (int ni = 0; ni < 4; ++ni)
                    acc[mi][ni] = __builtin_amdgcn_mfma_f32_16x16x32_bf16(afrag, bfrag[ni], acc[mi][ni], 0, 0, 0);
            }
        }
    }

    if (z == 2) {
        #pragma unroll
        for (int ni = 0; ni < 4; ++ni) {
            int colg = n0 + wc * 64 + ni * 16 + (lane & 15);
            float bj = bias[colg];
            int hh = colg >> 6, dd = colg & 63;
            #pragma unroll
            for (int mi = 0; mi < 2; ++mi) {
                int rbase = m0 + wr * 32 + mi * 16 + ((lane >> 4) << 2);
                int bb = rbase >> 9, ss = rbase & 511;
                ushort4 o;
                o.x = f2bf(acc[mi][ni][0] + bj);
                o.y = f2bf(acc[mi][ni][1] + bj);
                o.z = f2bf(acc[mi][ni][2] + bj);
                o.w = f2bf(acc[mi][ni][3] + bj);
                *reinterpret_cast<ushort4*>(out + ((size_t)(bb * NHEAD + hh) * DPH + dd) * S_LEN + ss) = o;
            }
        }
    } else {
        #pragma unroll
        for (int ni = 0; ni < 4; ++ni) {
            int colg = n0 + wc * 64 + ni * 16 + (lane & 15);
            float bj = bias[colg];
            #pragma unroll
            for (int mi = 0; mi < 2; ++mi) {
                int rbase = m0 + wr * 32 + mi * 16 + ((lane >> 4) << 2);
                #pragma unroll
                for (int q = 0; q < 4; ++q)
                    out[(size_t)(rbase + q) * EMB + colg] = f2bf(acc[mi][ni][q] + bj);
            }
        }
    }
}

// ---------------------------------------------------------------------------
// MFMA output GEMM, 64x128 tile, grid (4, 64) = 256 blocks = 1/CU (all CUs).
// A and B staged via global_load_lds w=16. out = f32 d_out.
// ---------------------------------------------------------------------------
__global__ __launch_bounds__(256) void gemm_out_mfma(
    const unsigned short* __restrict__ A,
    const unsigned short* __restrict__ W,
    const float* __restrict__ bias,
    float* __restrict__ out)
{
    const int n0 = blockIdx.x * 128;
    const int m0 = blockIdx.y * 64;
    const int tid = threadIdx.x;
    const int lane = tid & 63;
    const int wid = tid >> 6;
    const int wr = wid >> 1, wc = wid & 1;

    __shared__ __align__(16) unsigned char smA[64 * 64 * 2];
    __shared__ __align__(16) unsigned char smB[128 * 64 * 2];

    f32x4 acc[2][4] = {};

    for (int k0 = 0; k0 < EMB; k0 += 64) {
        __syncthreads();
        #pragma unroll
        for (int it = 0; it < 4; ++it) {
            int row = (it * 4 + wid) * 8 + (lane >> 3);
            int kcg = (lane & 7) ^ (row & 7);
            gload_lds16(W + (size_t)(n0 + row) * EMB + k0 + kcg * 8,
                        smB + (it * 4 + wid) * 1024);
        }
        #pragma unroll
        for (int it = 0; it < 2; ++it) {
            int row = (it * 4 + wid) * 8 + (lane >> 3);
            int kcg = (lane & 7) ^ (row & 7);
            gload_lds16(A + (size_t)(m0 + row) * EMB + k0 + kcg * 8,
                        smA + (it * 4 + wid) * 1024);
        }
        __syncthreads();

        #pragma unroll
        for (int ks = 0; ks < 2; ++ks) {
            bf16x8 bfrag[4];
            #pragma unroll
            for (int ni = 0; ni < 4; ++ni) {
                int col = wc * 64 + ni * 16 + (lane & 15);
                unsigned byte = ((unsigned)col << 7) + (unsigned)(ks << 6) + (unsigned)((lane >> 4) << 4);
                byte ^= (unsigned)((col & 7) << 4);
                bfrag[ni] = *reinterpret_cast<const bf16x8*>(smB + byte);
            }
            #pragma unroll
            for (int mi = 0; mi < 2; ++mi) {
                int row = wr * 32 + mi * 16 + (lane & 15);
                unsigned byte = ((unsigned)row << 7) + (unsigned)(ks << 6) + (unsigned)((lane >> 4) << 4);
                byte ^= (unsigned)((row & 7) << 4);
                bf16x8 afrag = *reinterpret_cast<const bf16x8*>(smA + byte);
                #pragma unroll
                for (int ni = 0; ni < 4; ++ni)
                    acc[mi][ni] = __builtin_amdgcn_mfma_f32_16x16x32_bf16(afrag, bfrag[ni], acc[mi][ni], 0, 0, 0);
            }
        }
    }

    #pragma unroll
    for (int ni = 0; ni < 4; ++ni) {
        int colg = n0 + wc * 64 + ni * 16 + (lane & 15);
        float bj = bias[colg];
        #pragma unroll
        for (int mi = 0; mi < 2; ++mi) {
            int rbase = m0 + wr * 32 + mi * 16 + ((lane >> 4) << 2);
            #pragma unroll
            for (int q = 0; q < 4; ++q)
                out[(size_t)(rbase + q) * EMB + colg] = acc[mi][ni][q] + bj;
        }
    }
}

// ---------------------------------------------------------------------------
// Relation-aware flash attention, v11 (validated 57.16 µs config):
// 8 waves (4 qstrips x 2 tgroups), 64-t tiles, 2 barriers/tile,
// no-max softmax, end-only reduce, P/Q LDS alias, XCD remap.
// ---------------------------------------------------------------------------
__global__ __launch_bounds__(512) void attn_mfma(
    const unsigned short* __restrict__ qb,
    const unsigned short* __restrict__ kb,
    const unsigned short* __restrict__ vbT,
    const int* __restrict__ rel,
    const float* __restrict__ rel_k, const float* __restrict__ rel_v,
    unsigned short* __restrict__ ob)
{
    const int gid = blockIdx.x + 8 * (blockIdx.y + 8 * blockIdx.z);
    const int bh  = (gid & 7) + 8 * ((gid >> 3) & 7);
    const int s0  = (gid >> 6) * 64;
    const int h   = bh & 7;
    const int b   = bh >> 3;
    const int tid = threadIdx.x;
    const int lane = tid & 63;
    const int wid = tid >> 6;          // 0..7
    const int qstrip = wid & 3;        // 16-row strip
    const int tgroup = wid >> 2;       // t-half
    const int sl = lane & 15;
    const int tg = lane >> 4;

    __shared__ __align__(16) unsigned char smQ[64 * 128];       // Q; P for waves 0-3 after prologue
    __shared__ __align__(16) unsigned char smK[2 * 64 * 128];   // per t-group; accL after loop
    __shared__ __align__(16) unsigned char smVt[2 * 64 * 128];  // per t-group; stats after loop
    __shared__ __align__(16) unsigned char smP2[4 * 16 * 128];  // P for waves 4-7
    __shared__ float qrel_s[64][4];
    __shared__ float relv_s[NREL][64];

    const unsigned short* qsrc  = qb + ((size_t)(b * S_LEN + s0)) * EMB + h * DPH;
    const unsigned short* ksrc  = kb + ((size_t)b * S_LEN) * EMB + h * DPH;
    const unsigned short* vsrcT = vbT + (size_t)(b * NHEAD + h) * DPH * S_LEN;

    // --- stage Q (64x64 bf16, swizzled): 512 thr x 1 uint4 ---
    {
        int row = tid >> 3, kc = tid & 7;
        uint4 raw = *reinterpret_cast<const uint4*>(qsrc + (size_t)row * EMB + kc * 8);
        unsigned byte = ((unsigned)row << 7) + ((unsigned)kc << 4);
        byte ^= (unsigned)((row & 7) << 4);
        *reinterpret_cast<uint4*>(smQ + byte) = raw;
    }
    if (tid < NREL * 64) {
        int rr = tid >> 6, d = tid & 63;
        relv_s[rr][d] = rel_v[rr * DPH + d];
    }
    __syncthreads();
    if (tid < 192) {
        int r = tid / 3, rr = tid - 3 * (tid / 3);
        float s = 0.f;
        #pragma unroll
        for (int dc = 0; dc < 32; ++dc) {
            unsigned byte = ((unsigned)r << 7) + (unsigned)(dc << 2);
            byte ^= (unsigned)((r & 7) << 4);
            unsigned u = *reinterpret_cast<const unsigned*>(smQ + byte);
            s += bf2f((unsigned short)(u & 0xffff)) * rel_k[rr * DPH + dc * 2]
               + bf2f((unsigned short)(u >> 16))   * rel_k[rr * DPH + dc * 2 + 1];
        }
        qrel_s[r][rr] = s;
    }
    __syncthreads();

    const int srow = qstrip * 16 + sl;
    const float CEXP  = 0.125f * 1.4426950408889634f;
    const float SHIFT = 11.541560327111707f;           // 8 * log2(e)
    const float qa0 = qrel_s[srow][0] * CEXP - SHIFT;
    const float qa1 = qrel_s[srow][1] * CEXP - SHIFT;
    const float qa2 = qrel_s[srow][2] * CEXP - SHIFT;

    bf16x8 qfrag[2];
    #pragma unroll
    for (int ks = 0; ks < 2; ++ks) {
        unsigned byte = ((unsigned)srow << 7) + (unsigned)(ks << 6) + (unsigned)(tg << 4);
        byte ^= (unsigned)((srow & 7) << 4);
        qfrag[ks] = *reinterpret_cast<const bf16x8*>(smQ + byte);
    }

    const int* rrow_s = rel + ((size_t)(b * S_LEN + s0 + srow)) * S_LEN;
    unsigned char* pb = (wid < 4) ? (smQ + wid * 2048) : (smP2 + (wid - 4) * 2048);

    const int gtid  = tid & 255;
    const int ldrow = gtid >> 3;
    const int ldkc  = gtid & 7;
    const unsigned wbyte0 = (((unsigned)ldrow << 7) + ((unsigned)ldkc << 4))
                            ^ ((unsigned)((ldrow & 7) << 4));
    const unsigned wbyte1 = wbyte0 + 4096;
    unsigned char* kbase = smK  + tgroup * 8192;
    unsigned char* vbase = smVt + tgroup * 8192;

    float l_run = 0.f, es1 = 0.f, es2 = 0.f;
    f32x4 acc_pv[4] = {};

    #pragma unroll
    for (int i = 0; i < 4; ++i) {
        const int t0 = (tgroup * 4 + i) * 64;

        uint4 k0 = *reinterpret_cast<const uint4*>(ksrc + (size_t)(t0 + ldrow) * EMB + ldkc * 8);
        uint4 k1 = *reinterpret_cast<const uint4*>(ksrc + (size_t)(t0 + ldrow + 32) * EMB + ldkc * 8);
        uint4 v0 = *reinterpret_cast<const uint4*>(vsrcT + (size_t)ldrow * S_LEN + t0 + ldkc * 8);
        uint4 v1 = *reinterpret_cast<const uint4*>(vsrcT + (size_t)(ldrow + 32) * S_LEN + t0 + ldkc * 8);
        int4 rr[4];
        #pragma unroll
        for (int t4 = 0; t4 < 4; ++t4)
            rr[t4] = *reinterpret_cast<const int4*>(rrow_s + t0 + t4 * 16 + tg * 4);

        __syncthreads();
        *reinterpret_cast<uint4*>(kbase + wbyte0) = k0;
        *reinterpret_cast<uint4*>(kbase + wbyte1) = k1;
        *reinterpret_cast<uint4*>(vbase + wbyte0) = v0;
        *reinterpret_cast<uint4*>(vbase + wbyte1) = v1;
        __syncthreads();

        f32x4 sacc[4] = {};
        #pragma unroll
        for (int ks = 0; ks < 2; ++ks)
            #pragma unroll
            for (int t4 = 0; t4 < 4; ++t4) {
                int trow = t4 * 16 + sl;
                unsigned byte = ((unsigned)trow << 7) + (unsigned)(ks << 6) + (unsigned)(tg << 4);
                byte ^= (unsigned)((trow & 7) << 4);
                bf16x8 kf = *reinterpret_cast<const bf16x8*>(kbase + byte);
                sacc[t4] = __builtin_amdgcn_mfma_f32_16x16x32_bf16(kf, qfrag[ks], sacc[t4], 0, 0, 0);
            }

        #pragma unroll
        for (int t4 = 0; t4 < 4; ++t4) {
            int rv[4] = {rr[t4].x, rr[t4].y, rr[t4].z, rr[t4].w};
            #pragma unroll
            for (int j = 0; j < 4; ++j) {
                int r = rv[j];
                float qa = (r == 0) ? qa0 : ((r == 1) ? qa1 : qa2);
                float p = __builtin_amdgcn_exp2f(fmaf(sacc[t4][j], CEXP, qa));
                sacc[t4][j] = p;
                l_run += p;
                es1 += (r == 1) ? p : 0.f;
                es2 += (r == 2) ? p : 0.f;
            }
        }

        #pragma unroll
        for (int t4 = 0; t4 < 4; ++t4)
            #pragma unroll
            for (int pr = 0; pr < 2; ++pr) {
                unsigned u = (unsigned)f2bf(sacc[t4][2 * pr]) |
                             ((unsigned)f2bf(sacc[t4][2 * pr + 1]) << 16);
                unsigned byte = ((unsigned)sl << 7) + (unsigned)(t4 * 32 + tg * 8 + pr * 4);
                byte ^= (unsigned)((sl & 7) << 4);
                *reinterpret_cast<unsigned*>(pb + byte) = u;
            }

        #pragma unroll
        for (int ks = 0; ks < 2; ++ks) {
            unsigned pbyte = ((unsigned)sl << 7) + (unsigned)(ks << 6) + (unsigned)(tg << 4);
            pbyte ^= (unsigned)((sl & 7) << 4);
            bf16x8 pf = *reinterpret_cast<const bf16x8*>(pb + pbyte);
            #pragma unroll
            for (int dt = 0; dt < 4; ++dt) {
                int d = dt * 16 + sl;
                unsigned vbyte = ((unsigned)d << 7) + (unsigned)(ks << 6) + (unsigned)(tg << 4);
                vbyte ^= (unsigned)((d & 7) << 4);
                bf16x8 vf = *reinterpret_cast<const bf16x8*>(vbase + vbyte);
                acc_pv[dt] = __builtin_amdgcn_mfma_f32_16x16x32_bf16(pf, vf, acc_pv[dt], 0, 0, 0);
            }
        }
    }

    l_run += __shfl_xor(l_run, 16);  l_run += __shfl_xor(l_run, 32);
    es1   += __shfl_xor(es1, 16);    es1   += __shfl_xor(es1, 32);
    es2   += __shfl_xor(es2, 16);    es2   += __shfl_xor(es2, 32);

    __syncthreads();
    float* accL  = reinterpret_cast<float*>(smK);
    float* stats = reinterpret_cast<float*>(smVt);

    if (tg == 0) {
        stats[tgroup * 64 + srow]        = l_run;
        stats[128 + tgroup * 64 + srow]  = es1;
        stats[256 + tgroup * 64 + srow]  = es2;
    }
    if (tgroup == 1) {
        #pragma unroll
        for (int dt = 0; dt < 4; ++dt)
            #pragma unroll
            for (int r = 0; r < 4; ++r)
                accL[(qstrip * 16 + tg * 4 + r) * 64 + dt * 16 + sl] = acc_pv[dt][r];
    }
    __syncthreads();

    if (tgroup == 0) {
        unsigned short* dst = ob + ((size_t)(b * S_LEN + s0 + qstrip * 16)) * EMB + h * DPH;
        #pragma unroll
        for (int r = 0; r < 4; ++r) {
            const int row64 = qstrip * 16 + tg * 4 + r;
            float lt  = stats[row64]       + stats[64 + row64];
            float e1t = stats[128 + row64] + stats[192 + row64];
            float e2t = stats[256 + row64] + stats[320 + row64];
            float e0t = lt - e1t - e2t;
            float linv = 1.f / lt;
            #pragma unroll
            for (int dt = 0; dt < 4; ++dt) {
                int d = dt * 16 + sl;
                float o = acc_pv[dt][r] + accL[row64 * 64 + d];
                o += e0t * relv_s[0][d] + e1t * relv_s[1][d] + e2t * relv_s[2][d];
                o *= linv;
                dst[(size_t)(tg * 4 + r) * EMB + d] = f2bf(o);
            }
        }
    }
}

extern "C" void kernel_launch(void* const* d_in, const int* in_sizes, int n_in,
                              void* d_out, int out_size, void* d_ws, size_t ws_size,
                              hipStream_t stream) {
    int iq=0, ik=1, iv=2, irel=3, iWq=4, ibq=5, iWk=6, ibk=7, iWv=8, ibv=9, iWo=10, ibo=11, irk=12, irv=13;
    if (n_in >= 14 && in_sizes[0] == 512 * 512) {
        iWk=0; iWo=1; iWq=2; iWv=3; ibk=4; ibo=5; ibq=6; ibv=7;
        irel=8; ik=9; iq=10; irk=11; irv=12; iv=13;
    }

    const float* q_in = (const float*)d_in[iq];
    const float* k_in = (const float*)d_in[ik];
    const float* v_in = (const float*)d_in[iv];
    const int*   grel = (const int*)d_in[irel];
    const float* Wq = (const float*)d_in[iWq];
    const float* bq = (const float*)d_in[ibq];
    const float* Wk = (const float*)d_in[iWk];
    const float* bk = (const float*)d_in[ibk];
    const float* Wv = (const float*)d_in[iWv];
    const float* bv = (const float*)d_in[ibv];
    const float* Wo = (const float*)d_in[iWo];
    const float* bo = (const float*)d_in[ibo];
    const float* rk = (const float*)d_in[irk];
    const float* rv = (const float*)d_in[irv];

    unsigned short* qb  = (unsigned short*)d_ws;
    unsigned short* kb  = qb + (size_t)4096 * 512;
    unsigned short* vbT = kb + (size_t)4096 * 512;   // [b*NHEAD+h][d][s]
    unsigned short* ab  = vbT + (size_t)4096 * 512;
    unsigned short* wt  = ab + (size_t)4096 * 512;

    dim3 blk(256);
    transpose_w<<<dim3(8, 8, 4), blk, 0, stream>>>(Wq, Wk, Wv, Wo, wt);
    gemm_proj_mfma<<<dim3(4, 64, 3), blk, 0, stream>>>(q_in, k_in, v_in, wt, bq, bk, bv, qb, kb, vbT);
    attn_mfma<<<dim3(8, NHEAD, BATCH), dim3(512), 0, stream>>>(qb, kb, vbT, grel, rk, rv, ab);
    gemm_out_mfma<<<dim3(4, 64), blk, 0, stream>>>(ab, wt + (size_t)3 * 512 * 512, bo, (float*)d_out);
}